// Round 7
// baseline (275.462 us; speedup 1.0000x reference)
//
#include <hip/hip_runtime.h>
#include <stdint.h>

typedef __bf16 bf16_t;
typedef __bf16 bf16x8 __attribute__((ext_vector_type(8)));
typedef __bf16 bf16x4 __attribute__((ext_vector_type(4)));
typedef float floatx4 __attribute__((ext_vector_type(4)));

__device__ __forceinline__ void async_copy16(const bf16_t* g, bf16_t* l) {
  __builtin_amdgcn_global_load_lds(
      (const __attribute__((address_space(1))) void*)g,
      (__attribute__((address_space(3))) void*)l, 16, 0, 0);
}

// ---------- converts (+ sync-counter reset for tail3) ----------
struct CvtSeg { const float* s; bf16_t* d; long n; };
struct CvtArgs { CvtSeg seg[5]; unsigned* sync; };

__global__ void cvt_multi(CvtArgs a) {
  if (blockIdx.x == 0 && blockIdx.y == 0 && threadIdx.x < 8)
    a.sync[threadIdx.x] = 0u;   // zeroed every iteration before tail3 runs
  CvtSeg sg = a.seg[blockIdx.y];
#pragma unroll
  for (int it = 0; it < 4; it++) {
    long i = (((long)blockIdx.x + (long)it * 2048) * 256 + threadIdx.x) * 4;
    if (i < sg.n) {
      float4 f = *(const float4*)(sg.s + i);
      bf16x4 o;
      o[0] = (bf16_t)f.x; o[1] = (bf16_t)f.y; o[2] = (bf16_t)f.z; o[3] = (bf16_t)f.w;
      *(bf16x4*)(sg.d + i) = o;
    }
  }
}

// ---------- fused q / kT / vT: 128x128 tile, LDS dbuf (round-5 proven, 62us) ----------
__global__ __launch_bounds__(256, 2) void qkv3(
    const bf16_t* __restrict__ xb,
    const bf16_t* __restrict__ Wq, const bf16_t* __restrict__ Wk, const bf16_t* __restrict__ Wv,
    const float* __restrict__ bq, const float* __restrict__ bk, const float* __restrict__ bv,
    bf16_t* __restrict__ qout, bf16_t* __restrict__ kT, bf16_t* __restrict__ vT) {
  __shared__ bf16_t As[2 * 4096];
  __shared__ bf16_t Bsh[3][2 * 4096];
  const int L = blockIdx.x;
  const int V = (L & 7) * 64 + (L >> 3);
  const int batch = V >> 7;
  const int rr_   = V & 127;
  const int n0 = (rr_ & 7) * 128;
  const int m0 = (rr_ >> 3) * 128;

  const int tid = threadIdx.x, lane = tid & 63, w = tid >> 6;
  const int wr = w >> 1, wc = w & 1, quad = lane >> 4, lm = lane & 15;
  const int ar = lane >> 2;
  const int ak = (((lane & 3) ^ ((ar >> 1) & 3))) * 8;
  const int swz = (lm >> 1) & 3;

  const bf16_t* ag0 = xb + (long)batch * (2048L * 1024) + (long)(m0 + w * 16 + ar) * 1024 + ak;
  const bf16_t* ag1 = ag0 + 64L * 1024;
  const bf16_t* Wp[3] = {Wq, Wk, Wv};
  const bf16_t* bg0[3];
  const bf16_t* bg1[3];
#pragma unroll
  for (int p = 0; p < 3; p++) {
    bg0[p] = Wp[p] + (long)(n0 + w * 16 + ar) * 1024 + ak;
    bg1[p] = bg0[p] + 64L * 1024;
  }

  floatx4 acc[3][4][4];
#pragma unroll
  for (int p = 0; p < 3; p++)
#pragma unroll
    for (int r = 0; r < 4; r++)
#pragma unroll
      for (int c = 0; c < 4; c++)
        acc[p][r][c] = (floatx4){0.f, 0.f, 0.f, 0.f};

  {
    bf16_t* la = As + w * 512;
    async_copy16(ag0, la);
    async_copy16(ag1, la + 2048);
#pragma unroll
    for (int p = 0; p < 3; p++) {
      bf16_t* lb = Bsh[p] + w * 512;
      async_copy16(bg0[p], lb);
      async_copy16(bg1[p], lb + 2048);
    }
  }
  for (int i = 0; i < 32; i++) {
    __syncthreads();
    if (i + 1 < 32) {
      const int buf = (i + 1) & 1, k0 = (i + 1) * 32;
      bf16_t* la = As + buf * 4096 + w * 512;
      async_copy16(ag0 + k0, la);
      async_copy16(ag1 + k0, la + 2048);
#pragma unroll
      for (int p = 0; p < 3; p++) {
        bf16_t* lb = Bsh[p] + buf * 4096 + w * 512;
        async_copy16(bg0[p] + k0, lb);
        async_copy16(bg1[p] + k0, lb + 2048);
      }
    }
    const bf16_t* Ar = As + (i & 1) * 4096;
    bf16x8 afr[4];
#pragma unroll
    for (int r = 0; r < 4; r++)
      afr[r] = *(const bf16x8*)&Ar[(wr * 64 + r * 16 + lm) * 32 + (quad ^ swz) * 8];
#pragma unroll
    for (int p = 0; p < 3; p++) {
      const bf16_t* Br = Bsh[p] + (i & 1) * 4096;
      bf16x8 bfr[4];
#pragma unroll
      for (int c = 0; c < 4; c++)
        bfr[c] = *(const bf16x8*)&Br[(wc * 64 + c * 16 + lm) * 32 + (quad ^ swz) * 8];
#pragma unroll
      for (int r = 0; r < 4; r++)
#pragma unroll
        for (int c = 0; c < 4; c++)
          acc[p][r][c] = __builtin_amdgcn_mfma_f32_16x16x32_bf16(afr[r], bfr[c], acc[p][r][c], 0, 0, 0);
    }
  }

  const int rowBase = m0 + wr * 64, colBase = n0 + wc * 64;
  {
    bf16_t* C = qout + (long)batch * (2048L * 1024);
#pragma unroll
    for (int r = 0; r < 4; r++) {
      const int row = rowBase + r * 16 + quad * 4;
#pragma unroll
      for (int c = 0; c < 4; c++) {
        const int col = colBase + c * 16 + lm;
        const float bv_ = bq[col];
#pragma unroll
        for (int i = 0; i < 4; i++)
          C[(long)(row + i) * 1024 + col] = (bf16_t)(acc[0][r][c][i] + bv_);
      }
    }
  }
#pragma unroll
  for (int p = 1; p < 3; p++) {
    bf16_t* C = ((p == 1) ? kT : vT) + (long)batch * (1024L * 2048);
    const float* bias = (p == 1) ? bk : bv;
#pragma unroll
    for (int r = 0; r < 4; r++) {
      const int row = rowBase + r * 16 + quad * 4;
#pragma unroll
      for (int c = 0; c < 4; c++) {
        const int col = colBase + c * 16 + lm;
        const float bv_ = bias[col];
        bf16x4 pk;
#pragma unroll
        for (int i = 0; i < 4; i++) pk[i] = (bf16_t)(acc[p][r][c][i] + bv_);
        *(bf16x4*)(C + (long)col * 2048 + row) = pk;
      }
    }
  }
}

// ---------- one 128x128 NT-gemm tile, wave-private LDS dbuf (round-3 proven body) ----------
// Ends with a full vmcnt drain so the caller can chain tiles/stages safely.
template<bool F32OUT, bool HAS_BIAS>
__device__ __forceinline__ void gemm_tile(
    bf16_t* Lw, const bf16_t* Ag, const bf16_t* Bg, void* Cb, const float* bias,
    int m0, int n0, int lda, int ldb, int nk, int ldc, float alpha,
    int wr, int wc, int quad, int lm, int ar, int ak, int swz) {
  const bf16_t* agA = Ag + (long)(m0 + wr * 64 + ar) * lda + ak;
  const bf16_t* agB = Bg + (long)(n0 + wc * 64 + ar) * ldb + ak;

  auto STAGE = [&](int t, int b) {
    const int k0 = t * 32;
    bf16_t* d = Lw + b * 4096;
#pragma unroll
    for (int j = 0; j < 4; j++)
      async_copy16(agA + (long)j * 16 * lda + k0, d + j * 512);
#pragma unroll
    for (int j = 0; j < 4; j++)
      async_copy16(agB + (long)j * 16 * ldb + k0, d + 2048 + j * 512);
  };

  floatx4 acc[4][4];
#pragma unroll
  for (int r = 0; r < 4; r++)
#pragma unroll
    for (int c = 0; c < 4; c++) acc[r][c] = (floatx4){0.f, 0.f, 0.f, 0.f};

  STAGE(0, 0);
  for (int i = 0; i < nk; i++) {
    if (i + 1 < nk) {
      STAGE(i + 1, (i + 1) & 1);
      asm volatile("s_waitcnt vmcnt(8)" ::: "memory");  // tile i's 8 loads done
    } else {
      asm volatile("s_waitcnt vmcnt(0)" ::: "memory");
    }
    const bf16_t* Aw = Lw + (i & 1) * 4096;
    const bf16_t* Bw = Aw + 2048;
    bf16x8 afr[4], bfr[4];
#pragma unroll
    for (int r = 0; r < 4; r++)
      afr[r] = *(const bf16x8*)&Aw[(r * 16 + lm) * 32 + (quad ^ swz) * 8];
#pragma unroll
    for (int c = 0; c < 4; c++)
      bfr[c] = *(const bf16x8*)&Bw[(c * 16 + lm) * 32 + (quad ^ swz) * 8];
#pragma unroll
    for (int r = 0; r < 4; r++)
#pragma unroll
      for (int c = 0; c < 4; c++)
        acc[r][c] = __builtin_amdgcn_mfma_f32_16x16x32_bf16(afr[r], bfr[c], acc[r][c], 0, 0, 0);
  }

  const int rowBase = m0 + wr * 64, colBase = n0 + wc * 64;
  if (!F32OUT) {
    bf16_t* Cp = (bf16_t*)Cb;
#pragma unroll
    for (int r = 0; r < 4; r++) {
      const int row = rowBase + r * 16 + quad * 4;
#pragma unroll
      for (int c = 0; c < 4; c++) {
        const int col = colBase + c * 16 + lm;
        const float bv_ = HAS_BIAS ? bias[col] : 0.f;
#pragma unroll
        for (int i = 0; i < 4; i++)
          Cp[(long)(row + i) * ldc + col] = (bf16_t)(acc[r][c][i] * alpha + bv_);
      }
    }
  } else {
    float* Cp = (float*)Cb;
#pragma unroll
    for (int r = 0; r < 4; r++) {
      const int row = rowBase + r * 16 + quad * 4;
#pragma unroll
      for (int c = 0; c < 4; c++) {
        const int col = colBase + c * 16 + lm;
        const float bv_ = HAS_BIAS ? bias[col] : 0.f;
#pragma unroll
        for (int i = 0; i < 4; i++)
          Cp[(long)(row + i) * ldc + col] = acc[r][c][i] * alpha + bv_;
      }
    }
  }
  // drain epilogue stores so later counted-vmcnt waits aren't aliased by them
  asm volatile("s_waitcnt vmcnt(0)" ::: "memory");
}

// ---------- fused downstream: Mt -> G -> final, one dispatch, global sync ----------
// 256 blocks x 96KB LDS => exactly 1 block/CU, all co-resident (spin is safe).
// Sync: monotonic counters (zeroed by cvt_multi each iteration), release add +
// acquire spin at AGENT scope (cross-XCD L2 wb/inv per AMDGPU memory model).
__global__ __launch_bounds__(256) void tail3(
    const bf16_t* __restrict__ kT, const bf16_t* __restrict__ vT,
    bf16_t* __restrict__ MtTb, bf16_t* __restrict__ Gb,
    const bf16_t* __restrict__ qb, const bf16_t* __restrict__ Wob,
    float* __restrict__ out, const float* __restrict__ bo,
    unsigned* __restrict__ sync) {
  __shared__ bf16_t Ls[49152];   // 96KB; first 64KB used (4 waves x 8192)
  const int L = blockIdx.x;
  const int V = (L & 7) * 32 + (L >> 3);   // XCD swizzle over 256 blocks

  const int tid = threadIdx.x, lane = tid & 63, w = tid >> 6;
  const int wr = w >> 1, wc = w & 1, quad = lane >> 4, lm = lane & 15;
  const int ar = lane >> 2;
  const int ak = (((lane & 3) ^ ((ar >> 1) & 3))) * 8;
  const int swz = (lm >> 1) & 3;
  bf16_t* Lw = Ls + w * 8192;

  auto gsync = [&](unsigned* c) {
    asm volatile("s_waitcnt vmcnt(0)" ::: "memory");
    __syncthreads();
    if (tid == 0) {
      __hip_atomic_fetch_add(c, 1u, __ATOMIC_RELEASE, __HIP_MEMORY_SCOPE_AGENT);
      while (__hip_atomic_load(c, __ATOMIC_ACQUIRE, __HIP_MEMORY_SCOPE_AGENT) < 256u)
        __builtin_amdgcn_s_sleep(2);
    }
    __syncthreads();
  };

  // ---- stage 1: MtT[f,e] = 0.125 * sum_t kT[f,t] * vT[e,t]  (4 x 64 tiles)
  {
    const int batch = V >> 6, r_ = V & 63;
    const int n0 = (r_ & 7) * 128, m0 = (r_ >> 3) * 128;
    gemm_tile<false, false>(Lw,
        kT + (long)batch * (1024L * 2048), vT + (long)batch * (1024L * 2048),
        MtTb + (long)batch * (1024L * 1024), nullptr,
        m0, n0, 2048, 2048, 64, 1024, 0.125f, wr, wc, quad, lm, ar, ak, swz);
  }
  gsync(sync + 0);

  // ---- stage 2: G[i,f] = sum_e Wo[i,e] * MtT[f,e]  (4 x 64 tiles)
  {
    const int batch = V >> 6, r_ = V & 63;
    const int n0 = (r_ & 7) * 128, m0 = (r_ >> 3) * 128;
    gemm_tile<false, false>(Lw,
        Wob, MtTb + (long)batch * (1024L * 1024),
        Gb + (long)batch * (1024L * 1024), nullptr,
        m0, n0, 1024, 1024, 32, 1024, 1.0f, wr, wc, quad, lm, ar, ak, swz);
  }
  gsync(sync + 1);

  // ---- stage 3: out[s,i] = sum_f q[s,f] * G[i,f] + bo[i]  (4 x 128 tiles, 2/block)
#pragma unroll
  for (int half = 0; half < 2; half++) {
    const int t = V + half * 256;
    const int batch = t >> 7, r_ = t & 127;
    const int n0 = (r_ & 7) * 128, m0 = (r_ >> 3) * 128;
    gemm_tile<true, true>(Lw,
        qb + (long)batch * (2048L * 1024), Gb + (long)batch * (1024L * 1024),
        out + (long)batch * (2048L * 1024), bo,
        m0, n0, 1024, 1024, 32, 1024, 1.0f, wr, wc, quad, lm, ar, ak, swz);
  }
}

extern "C" void kernel_launch(void* const* d_in, const int* in_sizes, int n_in,
                              void* d_out, int out_size, void* d_ws, size_t ws_size,
                              hipStream_t stream) {
  const float* x  = (const float*)d_in[0];
  const float* Wq = (const float*)d_in[1];
  const float* bq = (const float*)d_in[2];
  const float* Wk = (const float*)d_in[3];
  const float* bk = (const float*)d_in[4];
  const float* Wv = (const float*)d_in[5];
  const float* bv = (const float*)d_in[6];
  const float* Wo = (const float*)d_in[7];
  const float* bo = (const float*)d_in[8];
  float* out = (float*)d_out;

  const long NX = 8192L * 1024;      // 8M elems
  const long NW = 1024L * 1024;      // 1M elems

  bf16_t* ws  = (bf16_t*)d_ws;
  bf16_t* xb  = ws;                  // NX
  bf16_t* Wqb = xb + NX;
  bf16_t* Wkb = Wqb + NW;
  bf16_t* Wvb = Wkb + NW;
  bf16_t* Wob = Wvb + NW;
  bf16_t* qb  = Wob + NW;            // NX
  bf16_t* kT  = qb + NX;             // NX [B][E][S]
  bf16_t* vT  = kT + NX;             // NX [B][E][S]
  // reuse (stream-ordered):
  bf16_t* MtTb = xb;                 // 4M: [B][f][e], xb dead after qkv3
  bf16_t* Gb   = xb + 4 * NW;        // 4M: [B][i][f] (xb region, disjoint from MtTb)
  unsigned* sync = (unsigned*)(ws + 36L * 1024 * 1024);  // 72MB offset, 32B

  CvtArgs ca;
  ca.seg[0] = {x,  xb,  NX};
  ca.seg[1] = {Wq, Wqb, NW};
  ca.seg[2] = {Wk, Wkb, NW};
  ca.seg[3] = {Wv, Wvb, NW};
  ca.seg[4] = {Wo, Wob, NW};
  ca.sync = sync;
  cvt_multi<<<dim3(2048, 5), 256, 0, stream>>>(ca);

  // q / kT / vT fused, 128x128, 2 blocks/CU (round-5 best: ~62us)
  qkv3<<<dim3(512), 256, 0, stream>>>(xb, Wqb, Wkb, Wvb, bq, bk, bv, qb, kT, vT);

  // fused downstream chain: Mt -> G -> final with in-kernel grid sync
  tail3<<<dim3(256), 256, 0, stream>>>(kT, vT, MtTb, Gb, qb, Wob, out, bo, sync);
}

// Round 8
// 250.492 us; speedup vs baseline: 1.0997x; 1.0997x over previous
//
#include <hip/hip_runtime.h>
#include <stdint.h>

typedef __bf16 bf16_t;
typedef __bf16 bf16x8 __attribute__((ext_vector_type(8)));
typedef __bf16 bf16x4 __attribute__((ext_vector_type(4)));
typedef float floatx4 __attribute__((ext_vector_type(4)));

__device__ __forceinline__ void async_copy16(const bf16_t* g, bf16_t* l) {
  __builtin_amdgcn_global_load_lds(
      (const __attribute__((address_space(1))) void*)g,
      (__attribute__((address_space(3))) void*)l, 16, 0, 0);
}

// ---------- converts ----------
struct CvtSeg { const float* s; bf16_t* d; long n; };
struct CvtArgs { CvtSeg seg[5]; };

__global__ void cvt_multi(CvtArgs a) {
  CvtSeg sg = a.seg[blockIdx.y];
#pragma unroll
  for (int it = 0; it < 4; it++) {
    long i = (((long)blockIdx.x + (long)it * 2048) * 256 + threadIdx.x) * 4;
    if (i < sg.n) {
      float4 f = *(const float4*)(sg.s + i);
      bf16x4 o;
      o[0] = (bf16_t)f.x; o[1] = (bf16_t)f.y; o[2] = (bf16_t)f.z; o[3] = (bf16_t)f.w;
      *(bf16x4*)(sg.d + i) = o;
    }
  }
}

// ---------- split-K reduces ----------
// msum4: d[i] = sum of 4 parts; parts 0,1 at s0 (+4M), parts 2,3 at s1 (+4M). 4M elems.
__global__ void msum4(const bf16_t* __restrict__ s0, const bf16_t* __restrict__ s1,
                      bf16_t* __restrict__ d) {
  const long i = ((long)blockIdx.x * 256 + threadIdx.x) * 8;
  bf16x8 a = *(const bf16x8*)(s0 + i);
  bf16x8 b = *(const bf16x8*)(s0 + i + 4194304);
  bf16x8 c = *(const bf16x8*)(s1 + i);
  bf16x8 e = *(const bf16x8*)(s1 + i + 4194304);
  bf16x8 o;
#pragma unroll
  for (int j = 0; j < 8; j++)
    o[j] = (bf16_t)((float)a[j] + (float)b[j] + (float)c[j] + (float)e[j]);
  *(bf16x8*)(d + i) = o;
}

// psum2: d[i] = s0[i] + s1[i]. 8M elems.
__global__ void psum2(const bf16_t* __restrict__ s0, const bf16_t* __restrict__ s1,
                      bf16_t* __restrict__ d) {
  const long i = ((long)blockIdx.x * 256 + threadIdx.x) * 8;
  bf16x8 a = *(const bf16x8*)(s0 + i);
  bf16x8 b = *(const bf16x8*)(s1 + i);
  bf16x8 o;
#pragma unroll
  for (int j = 0; j < 8; j++) o[j] = (bf16_t)((float)a[j] + (float)b[j]);
  *(bf16x8*)(d + i) = o;
}

// ---------- fused q / kT / vT: 128x128 tile, LDS dbuf (round-5 proven, 62us) ----------
__global__ __launch_bounds__(256, 2) void qkv3(
    const bf16_t* __restrict__ xb,
    const bf16_t* __restrict__ Wq, const bf16_t* __restrict__ Wk, const bf16_t* __restrict__ Wv,
    const float* __restrict__ bq, const float* __restrict__ bk, const float* __restrict__ bv,
    bf16_t* __restrict__ qout, bf16_t* __restrict__ kT, bf16_t* __restrict__ vT) {
  __shared__ bf16_t As[2 * 4096];
  __shared__ bf16_t Bsh[3][2 * 4096];
  const int L = blockIdx.x;
  const int V = (L & 7) * 64 + (L >> 3);
  const int batch = V >> 7;
  const int rr_   = V & 127;
  const int n0 = (rr_ & 7) * 128;
  const int m0 = (rr_ >> 3) * 128;

  const int tid = threadIdx.x, lane = tid & 63, w = tid >> 6;
  const int wr = w >> 1, wc = w & 1, quad = lane >> 4, lm = lane & 15;
  const int ar = lane >> 2;
  const int ak = (((lane & 3) ^ ((ar >> 1) & 3))) * 8;
  const int swz = (lm >> 1) & 3;

  const bf16_t* ag0 = xb + (long)batch * (2048L * 1024) + (long)(m0 + w * 16 + ar) * 1024 + ak;
  const bf16_t* ag1 = ag0 + 64L * 1024;
  const bf16_t* Wp[3] = {Wq, Wk, Wv};
  const bf16_t* bg0[3];
  const bf16_t* bg1[3];
#pragma unroll
  for (int p = 0; p < 3; p++) {
    bg0[p] = Wp[p] + (long)(n0 + w * 16 + ar) * 1024 + ak;
    bg1[p] = bg0[p] + 64L * 1024;
  }

  floatx4 acc[3][4][4];
#pragma unroll
  for (int p = 0; p < 3; p++)
#pragma unroll
    for (int r = 0; r < 4; r++)
#pragma unroll
      for (int c = 0; c < 4; c++)
        acc[p][r][c] = (floatx4){0.f, 0.f, 0.f, 0.f};

  {
    bf16_t* la = As + w * 512;
    async_copy16(ag0, la);
    async_copy16(ag1, la + 2048);
#pragma unroll
    for (int p = 0; p < 3; p++) {
      bf16_t* lb = Bsh[p] + w * 512;
      async_copy16(bg0[p], lb);
      async_copy16(bg1[p], lb + 2048);
    }
  }
  for (int i = 0; i < 32; i++) {
    __syncthreads();
    if (i + 1 < 32) {
      const int buf = (i + 1) & 1, k0 = (i + 1) * 32;
      bf16_t* la = As + buf * 4096 + w * 512;
      async_copy16(ag0 + k0, la);
      async_copy16(ag1 + k0, la + 2048);
#pragma unroll
      for (int p = 0; p < 3; p++) {
        bf16_t* lb = Bsh[p] + buf * 4096 + w * 512;
        async_copy16(bg0[p] + k0, lb);
        async_copy16(bg1[p] + k0, lb + 2048);
      }
    }
    const bf16_t* Ar = As + (i & 1) * 4096;
    bf16x8 afr[4];
#pragma unroll
    for (int r = 0; r < 4; r++)
      afr[r] = *(const bf16x8*)&Ar[(wr * 64 + r * 16 + lm) * 32 + (quad ^ swz) * 8];
#pragma unroll
    for (int p = 0; p < 3; p++) {
      const bf16_t* Br = Bsh[p] + (i & 1) * 4096;
      bf16x8 bfr[4];
#pragma unroll
      for (int c = 0; c < 4; c++)
        bfr[c] = *(const bf16x8*)&Br[(wc * 64 + c * 16 + lm) * 32 + (quad ^ swz) * 8];
#pragma unroll
      for (int r = 0; r < 4; r++)
#pragma unroll
        for (int c = 0; c < 4; c++)
          acc[p][r][c] = __builtin_amdgcn_mfma_f32_16x16x32_bf16(afr[r], bfr[c], acc[p][r][c], 0, 0, 0);
    }
  }

  const int rowBase = m0 + wr * 64, colBase = n0 + wc * 64;
  {
    bf16_t* C = qout + (long)batch * (2048L * 1024);
#pragma unroll
    for (int r = 0; r < 4; r++) {
      const int row = rowBase + r * 16 + quad * 4;
#pragma unroll
      for (int c = 0; c < 4; c++) {
        const int col = colBase + c * 16 + lm;
        const float bv_ = bq[col];
#pragma unroll
        for (int i = 0; i < 4; i++)
          C[(long)(row + i) * 1024 + col] = (bf16_t)(acc[0][r][c][i] + bv_);
      }
    }
  }
#pragma unroll
  for (int p = 1; p < 3; p++) {
    bf16_t* C = ((p == 1) ? kT : vT) + (long)batch * (1024L * 2048);
    const float* bias = (p == 1) ? bk : bv;
#pragma unroll
    for (int r = 0; r < 4; r++) {
      const int row = rowBase + r * 16 + quad * 4;
#pragma unroll
      for (int c = 0; c < 4; c++) {
        const int col = colBase + c * 16 + lm;
        const float bv_ = bias[col];
        bf16x4 pk;
#pragma unroll
        for (int i = 0; i < 4; i++) pk[i] = (bf16_t)(acc[p][r][c][i] + bv_);
        *(bf16x4*)(C + (long)col * 2048 + row) = pk;
      }
    }
  }
}

// ---------- NT GEMM, 128x128 tile, shared 2-phase dbuf, split-K grids ----------
// 32KB LDS + __launch_bounds__(256,4) -> 4 blocks/CU when grid >= 1024.
// Split-K parts: kp < KSPLIT/2 -> C0 else C1; within a base, part stride pS.
// OUT_MODE 0: bf16; 2: fp32 (+bias). N fixed at 1024 (8 n-tiles).
template<int OUT_MODE, bool HAS_BIAS, int TOTAL, int BPZ, int KSPLIT>
__global__ __launch_bounds__(256, 4) void gemm_ks(
    const bf16_t* __restrict__ A, const bf16_t* __restrict__ B,
    void* __restrict__ C0, void* __restrict__ C1, const float* __restrict__ bias,
    int lda, int ldb, int nk, long sA, long sB, long pS, long sC, int ldc, float alpha) {
  __shared__ bf16_t As[2 * 4096];   // 128 x 32 per buffer
  __shared__ bf16_t Bs[2 * 4096];
  const int L = blockIdx.x;
  const int V = (L & 7) * (TOTAL / 8) + (L >> 3);
  const int zz = V / BPZ;
  const int r_ = V % BPZ;
  const int batch = zz / KSPLIT;
  const int kp = zz % KSPLIT;
  const long koff = (long)kp * ((long)nk * 32);
  const int n0 = (r_ & 7) * 128;
  const int m0 = (r_ >> 3) * 128;

  const int tid = threadIdx.x, lane = tid & 63, w = tid >> 6;
  const int wr = w >> 1, wc = w & 1, quad = lane >> 4, lm = lane & 15;
  const int ar = lane >> 2;
  const int ak = (((lane & 3) ^ ((ar >> 1) & 3))) * 8;
  const int swz = (lm >> 1) & 3;

  const bf16_t* Ab = A + (long)batch * sA + koff;
  const bf16_t* Bb = B + (long)batch * sB + koff;
  const bf16_t* ag0 = Ab + (long)(m0 + w * 16 + ar) * lda + ak;
  const bf16_t* ag1 = ag0 + (long)64 * lda;
  const bf16_t* bg0 = Bb + (long)(n0 + w * 16 + ar) * ldb + ak;
  const bf16_t* bg1 = bg0 + (long)64 * ldb;

  floatx4 acc[4][4];
#pragma unroll
  for (int r = 0; r < 4; r++)
#pragma unroll
    for (int c = 0; c < 4; c++) acc[r][c] = (floatx4){0.f, 0.f, 0.f, 0.f};

  {
    async_copy16(ag0, As + w * 512);
    async_copy16(ag1, As + w * 512 + 2048);
    async_copy16(bg0, Bs + w * 512);
    async_copy16(bg1, Bs + w * 512 + 2048);
  }
  for (int i = 0; i < nk; i++) {
    __syncthreads();
    if (i + 1 < nk) {
      const int buf = (i + 1) & 1, k0 = (i + 1) * 32;
      async_copy16(ag0 + k0, As + buf * 4096 + w * 512);
      async_copy16(ag1 + k0, As + buf * 4096 + w * 512 + 2048);
      async_copy16(bg0 + k0, Bs + buf * 4096 + w * 512);
      async_copy16(bg1 + k0, Bs + buf * 4096 + w * 512 + 2048);
    }
    const bf16_t* Ar = As + (i & 1) * 4096;
    const bf16_t* Br = Bs + (i & 1) * 4096;
    bf16x8 afr[4], bfr[4];
#pragma unroll
    for (int r = 0; r < 4; r++)
      afr[r] = *(const bf16x8*)&Ar[(wr * 64 + r * 16 + lm) * 32 + (quad ^ swz) * 8];
#pragma unroll
    for (int c = 0; c < 4; c++)
      bfr[c] = *(const bf16x8*)&Br[(wc * 64 + c * 16 + lm) * 32 + (quad ^ swz) * 8];
#pragma unroll
    for (int r = 0; r < 4; r++)
#pragma unroll
      for (int c = 0; c < 4; c++)
        acc[r][c] = __builtin_amdgcn_mfma_f32_16x16x32_bf16(afr[r], bfr[c], acc[r][c], 0, 0, 0);
  }

  const int rowBase = m0 + wr * 64, colBase = n0 + wc * 64;
  if (OUT_MODE == 0) {
    bf16_t* Cp;
    if (KSPLIT == 1) {
      Cp = (bf16_t*)C0 + (long)batch * sC;
    } else {
      bf16_t* base = (bf16_t*)((kp < KSPLIT / 2) ? C0 : C1);
      Cp = base + (long)(kp % (KSPLIT / 2)) * pS + (long)batch * sC;
    }
#pragma unroll
    for (int r = 0; r < 4; r++) {
      const int row = rowBase + r * 16 + quad * 4;
#pragma unroll
      for (int c = 0; c < 4; c++) {
        const int col = colBase + c * 16 + lm;
        const float bv_ = HAS_BIAS ? bias[col] : 0.f;
#pragma unroll
        for (int i = 0; i < 4; i++)
          Cp[(long)(row + i) * ldc + col] = (bf16_t)(acc[r][c][i] * alpha + bv_);
      }
    }
  } else {
    float* Cp = (float*)C0 + (long)batch * sC;
#pragma unroll
    for (int r = 0; r < 4; r++) {
      const int row = rowBase + r * 16 + quad * 4;
#pragma unroll
      for (int c = 0; c < 4; c++) {
        const int col = colBase + c * 16 + lm;
        const float bv_ = HAS_BIAS ? bias[col] : 0.f;
#pragma unroll
        for (int i = 0; i < 4; i++)
          Cp[(long)(row + i) * ldc + col] = acc[r][c][i] * alpha + bv_;
      }
    }
  }
}

extern "C" void kernel_launch(void* const* d_in, const int* in_sizes, int n_in,
                              void* d_out, int out_size, void* d_ws, size_t ws_size,
                              hipStream_t stream) {
  const float* x  = (const float*)d_in[0];
  const float* Wq = (const float*)d_in[1];
  const float* bq = (const float*)d_in[2];
  const float* Wk = (const float*)d_in[3];
  const float* bk = (const float*)d_in[4];
  const float* Wv = (const float*)d_in[5];
  const float* bv = (const float*)d_in[6];
  const float* Wo = (const float*)d_in[7];
  const float* bo = (const float*)d_in[8];
  float* out = (float*)d_out;

  const long NX = 8192L * 1024;      // 8M elems
  const long NW = 1024L * 1024;      // 1M elems

  bf16_t* ws  = (bf16_t*)d_ws;
  bf16_t* xb  = ws;                  // NX (16MB)
  bf16_t* Wqb = xb + NX;
  bf16_t* Wkb = Wqb + NW;
  bf16_t* Wvb = Wkb + NW;
  bf16_t* Wob = Wvb + NW;
  bf16_t* qb  = Wob + NW;            // NX
  bf16_t* kT  = qb + NX;             // NX [B][E][S]
  bf16_t* vT  = kT + NX;             // NX [B][E][S]
  bf16_t* outb = (bf16_t*)out;       // d_out as 16MB bf16 scratch (pre-final)
  // reuse (stream-ordered):
  //  M parts 0,1 -> xb[0],xb[4M];  parts 2,3 -> outb[0],outb[4M]
  bf16_t* Mtb = kT;                  // 4M: [B][e][f], kT dead after M gemm
  //  P parts: part0 -> xb, part1 -> outb (both dead after msum4)
  bf16_t* Pb  = vT;                  // 8M: [B][s][e], vT dead after M gemm

  CvtArgs ca;
  ca.seg[0] = {x,  xb,  NX};
  ca.seg[1] = {Wq, Wqb, NW};
  ca.seg[2] = {Wk, Wkb, NW};
  ca.seg[3] = {Wv, Wvb, NW};
  ca.seg[4] = {Wo, Wob, NW};
  cvt_multi<<<dim3(2048, 5), 256, 0, stream>>>(ca);

  // q / kT / vT fused, 128x128, 2 blocks/CU (round-5 proven: ~62us)
  qkv3<<<dim3(512), 256, 0, stream>>>(xb, Wqb, Wkb, Wvb, bq, bk, bv, qb, kT, vT);

  // M[e,f] = 0.125 * sum_t vT[e,t]*kT[f,t]; split-K=4 -> 1024 blocks (4/CU), nk=16
  // parts layout [kp][b][e][f]: kp 0,1 in xb; kp 2,3 in outb; pS=4M, sC=1M
  gemm_ks<0, false, 1024, 64, 4><<<dim3(1024), 256, 0, stream>>>(
      vT, kT, xb, outb, nullptr, 2048, 2048, 16,
      1024L * 2048, 1024L * 2048, 4194304L, 1024L * 1024, 1024, 0.125f);

  // Mtb = sum of 4 parts -> kT (dead)
  msum4<<<dim3(2048), 256, 0, stream>>>(xb, outb, Mtb);

  // P[s,e] = sum_f q[s,f]*M[e,f]; split-K=2 -> 1024 blocks (4/CU), nk=16
  // parts [kp][b][s][e]: kp0 in xb, kp1 in outb; sC=2M
  gemm_ks<0, false, 1024, 128, 2><<<dim3(1024), 256, 0, stream>>>(
      qb, Mtb, xb, outb, nullptr, 1024, 1024, 16,
      2048L * 1024, 1024L * 1024, 0L, 2048L * 1024, 1024, 1.0f);

  // Pb = part0 + part1 -> vT (dead)
  psum2<<<dim3(4096), 256, 0, stream>>>(xb, outb, Pb);

  // out[s,i] = sum_e P[s,e]*Wo[i,e] + bo[i]; 512 blocks, fp32 out
  gemm_ks<2, true, 512, 128, 1><<<dim3(512), 256, 0, stream>>>(
      Pb, Wob, out, nullptr, bo, 1024, 1024, 32,
      2048L * 1024, 0L, 0L, 2048L * 1024, 1024, 1.0f);
}

// Round 9
// 234.777 us; speedup vs baseline: 1.1733x; 1.0669x over previous
//
#include <hip/hip_runtime.h>
#include <stdint.h>

typedef __bf16 bf16_t;
typedef __bf16 bf16x8 __attribute__((ext_vector_type(8)));
typedef __bf16 bf16x4 __attribute__((ext_vector_type(4)));
typedef float floatx4 __attribute__((ext_vector_type(4)));

__device__ __forceinline__ void async_copy16(const bf16_t* g, bf16_t* l) {
  __builtin_amdgcn_global_load_lds(
      (const __attribute__((address_space(1))) void*)g,
      (__attribute__((address_space(3))) void*)l, 16, 0, 0);
}

// ---------- converts ----------
struct CvtSeg { const float* s; bf16_t* d; long n; };
struct CvtArgs { CvtSeg seg[5]; };

__global__ void cvt_multi(CvtArgs a) {
  CvtSeg sg = a.seg[blockIdx.y];
#pragma unroll
  for (int it = 0; it < 4; it++) {
    long i = (((long)blockIdx.x + (long)it * 2048) * 256 + threadIdx.x) * 4;
    if (i < sg.n) {
      float4 f = *(const float4*)(sg.s + i);
      bf16x4 o;
      o[0] = (bf16_t)f.x; o[1] = (bf16_t)f.y; o[2] = (bf16_t)f.z; o[3] = (bf16_t)f.w;
      *(bf16x4*)(sg.d + i) = o;
    }
  }
}

// ---------- fused q / kT / vT: 128x128 tile, LDS dbuf (round-5 proven, ~60us) ----------
__global__ __launch_bounds__(256, 2) void qkv3(
    const bf16_t* __restrict__ xb,
    const bf16_t* __restrict__ Wq, const bf16_t* __restrict__ Wk, const bf16_t* __restrict__ Wv,
    const float* __restrict__ bq, const float* __restrict__ bk, const float* __restrict__ bv,
    bf16_t* __restrict__ qout, bf16_t* __restrict__ kT, bf16_t* __restrict__ vT) {
  __shared__ bf16_t As[2 * 4096];
  __shared__ bf16_t Bsh[3][2 * 4096];
  const int L = blockIdx.x;
  const int V = (L & 7) * 64 + (L >> 3);
  const int batch = V >> 7;
  const int rr_   = V & 127;
  const int n0 = (rr_ & 7) * 128;
  const int m0 = (rr_ >> 3) * 128;

  const int tid = threadIdx.x, lane = tid & 63, w = tid >> 6;
  const int wr = w >> 1, wc = w & 1, quad = lane >> 4, lm = lane & 15;
  const int ar = lane >> 2;
  const int ak = (((lane & 3) ^ ((ar >> 1) & 3))) * 8;
  const int swz = (lm >> 1) & 3;

  const bf16_t* ag0 = xb + (long)batch * (2048L * 1024) + (long)(m0 + w * 16 + ar) * 1024 + ak;
  const bf16_t* ag1 = ag0 + 64L * 1024;
  const bf16_t* Wp[3] = {Wq, Wk, Wv};
  const bf16_t* bg0[3];
  const bf16_t* bg1[3];
#pragma unroll
  for (int p = 0; p < 3; p++) {
    bg0[p] = Wp[p] + (long)(n0 + w * 16 + ar) * 1024 + ak;
    bg1[p] = bg0[p] + 64L * 1024;
  }

  floatx4 acc[3][4][4];
#pragma unroll
  for (int p = 0; p < 3; p++)
#pragma unroll
    for (int r = 0; r < 4; r++)
#pragma unroll
      for (int c = 0; c < 4; c++)
        acc[p][r][c] = (floatx4){0.f, 0.f, 0.f, 0.f};

  {
    bf16_t* la = As + w * 512;
    async_copy16(ag0, la);
    async_copy16(ag1, la + 2048);
#pragma unroll
    for (int p = 0; p < 3; p++) {
      bf16_t* lb = Bsh[p] + w * 512;
      async_copy16(bg0[p], lb);
      async_copy16(bg1[p], lb + 2048);
    }
  }
  for (int i = 0; i < 32; i++) {
    __syncthreads();
    if (i + 1 < 32) {
      const int buf = (i + 1) & 1, k0 = (i + 1) * 32;
      bf16_t* la = As + buf * 4096 + w * 512;
      async_copy16(ag0 + k0, la);
      async_copy16(ag1 + k0, la + 2048);
#pragma unroll
      for (int p = 0; p < 3; p++) {
        bf16_t* lb = Bsh[p] + buf * 4096 + w * 512;
        async_copy16(bg0[p] + k0, lb);
        async_copy16(bg1[p] + k0, lb + 2048);
      }
    }
    const bf16_t* Ar = As + (i & 1) * 4096;
    bf16x8 afr[4];
#pragma unroll
    for (int r = 0; r < 4; r++)
      afr[r] = *(const bf16x8*)&Ar[(wr * 64 + r * 16 + lm) * 32 + (quad ^ swz) * 8];
#pragma unroll
    for (int p = 0; p < 3; p++) {
      const bf16_t* Br = Bsh[p] + (i & 1) * 4096;
      bf16x8 bfr[4];
#pragma unroll
      for (int c = 0; c < 4; c++)
        bfr[c] = *(const bf16x8*)&Br[(wc * 64 + c * 16 + lm) * 32 + (quad ^ swz) * 8];
#pragma unroll
      for (int r = 0; r < 4; r++)
#pragma unroll
        for (int c = 0; c < 4; c++)
          acc[p][r][c] = __builtin_amdgcn_mfma_f32_16x16x32_bf16(afr[r], bfr[c], acc[p][r][c], 0, 0, 0);
    }
  }

  const int rowBase = m0 + wr * 64, colBase = n0 + wc * 64;
  {
    bf16_t* C = qout + (long)batch * (2048L * 1024);
#pragma unroll
    for (int r = 0; r < 4; r++) {
      const int row = rowBase + r * 16 + quad * 4;
#pragma unroll
      for (int c = 0; c < 4; c++) {
        const int col = colBase + c * 16 + lm;
        const float bv_ = bq[col];
#pragma unroll
        for (int i = 0; i < 4; i++)
          C[(long)(row + i) * 1024 + col] = (bf16_t)(acc[0][r][c][i] + bv_);
      }
    }
  }
#pragma unroll
  for (int p = 1; p < 3; p++) {
    bf16_t* C = ((p == 1) ? kT : vT) + (long)batch * (1024L * 2048);
    const float* bias = (p == 1) ? bk : bv;
#pragma unroll
    for (int r = 0; r < 4; r++) {
      const int row = rowBase + r * 16 + quad * 4;
#pragma unroll
      for (int c = 0; c < 4; c++) {
        const int col = colBase + c * 16 + lm;
        const float bv_ = bias[col];
        bf16x4 pk;
#pragma unroll
        for (int i = 0; i < 4; i++) pk[i] = (bf16_t)(acc[p][r][c][i] + bv_);
        *(bf16x4*)(C + (long)col * 2048 + row) = pk;
      }
    }
  }
}

// ---------- NT GEMM, 128x128 tile, BK=64 (two 128x32 planes), shared dbuf ----------
// Per K-step: 8 staging instr/wave + 32 MFMA/wave — qkv3's per-step density.
// Each BK-half plane is byte-identical to the proven 128x32 layout (same source
// pre-swizzle ak, same (quad^swz) read), so no new bank-conflict risk.
// LDS 64KB -> 2 blocks/CU when grid >= 512.
// OUT_MODE 0: bf16; 2: fp32 (+bias). N fixed at 1024 (8 n-tiles).
template<int OUT_MODE, bool HAS_BIAS, int TOTAL, int BPZ>
__global__ __launch_bounds__(256, 2) void gemm64(
    const bf16_t* __restrict__ A, const bf16_t* __restrict__ B,
    void* __restrict__ C, const float* __restrict__ bias,
    int lda, int ldb, int nk, long sA, long sB, long sC, int ldc, float alpha) {
  __shared__ bf16_t As[2][2][4096];   // [buf][plane][128x32]
  __shared__ bf16_t Bs[2][2][4096];
  const int L = blockIdx.x;
  const int V = (L & 7) * (TOTAL / 8) + (L >> 3);
  const int batch = V / BPZ;
  const int r_ = V % BPZ;
  const int n0 = (r_ & 7) * 128;
  const int m0 = (r_ >> 3) * 128;

  const int tid = threadIdx.x, lane = tid & 63, w = tid >> 6;
  const int wr = w >> 1, wc = w & 1, quad = lane >> 4, lm = lane & 15;
  const int ar = lane >> 2;
  const int ak = (((lane & 3) ^ ((ar >> 1) & 3))) * 8;
  const int swz = (lm >> 1) & 3;

  const bf16_t* Ab = A + (long)batch * sA;
  const bf16_t* Bb = B + (long)batch * sB;
  const bf16_t* ag0 = Ab + (long)(m0 + w * 16 + ar) * lda + ak;
  const bf16_t* ag1 = ag0 + (long)64 * lda;
  const bf16_t* bg0 = Bb + (long)(n0 + w * 16 + ar) * ldb + ak;
  const bf16_t* bg1 = bg0 + (long)64 * ldb;

  auto STAGE = [&](int t, int buf) {
    const int k0 = t * 64;
#pragma unroll
    for (int p = 0; p < 2; p++) {
      const int kp = k0 + p * 32;
      async_copy16(ag0 + kp, &As[buf][p][w * 512]);
      async_copy16(ag1 + kp, &As[buf][p][w * 512 + 2048]);
      async_copy16(bg0 + kp, &Bs[buf][p][w * 512]);
      async_copy16(bg1 + kp, &Bs[buf][p][w * 512 + 2048]);
    }
  };

  floatx4 acc[4][4];
#pragma unroll
  for (int r = 0; r < 4; r++)
#pragma unroll
    for (int c = 0; c < 4; c++) acc[r][c] = (floatx4){0.f, 0.f, 0.f, 0.f};

  STAGE(0, 0);
  for (int i = 0; i < nk; i++) {
    __syncthreads();
    if (i + 1 < nk) STAGE(i + 1, (i + 1) & 1);
    const int cb = i & 1;
#pragma unroll
    for (int p = 0; p < 2; p++) {
      bf16x8 afr[4], bfr[4];
#pragma unroll
      for (int r = 0; r < 4; r++)
        afr[r] = *(const bf16x8*)&As[cb][p][(wr * 64 + r * 16 + lm) * 32 + (quad ^ swz) * 8];
#pragma unroll
      for (int c = 0; c < 4; c++)
        bfr[c] = *(const bf16x8*)&Bs[cb][p][(wc * 64 + c * 16 + lm) * 32 + (quad ^ swz) * 8];
#pragma unroll
      for (int r = 0; r < 4; r++)
#pragma unroll
        for (int c = 0; c < 4; c++)
          acc[r][c] = __builtin_amdgcn_mfma_f32_16x16x32_bf16(afr[r], bfr[c], acc[r][c], 0, 0, 0);
    }
  }

  const int rowBase = m0 + wr * 64, colBase = n0 + wc * 64;
  if (OUT_MODE == 0) {
    bf16_t* Cb = (bf16_t*)C + (long)batch * sC;
#pragma unroll
    for (int r = 0; r < 4; r++) {
      const int row = rowBase + r * 16 + quad * 4;
#pragma unroll
      for (int c = 0; c < 4; c++) {
        const int col = colBase + c * 16 + lm;
        const float bv_ = HAS_BIAS ? bias[col] : 0.f;
#pragma unroll
        for (int i = 0; i < 4; i++)
          Cb[(long)(row + i) * ldc + col] = (bf16_t)(acc[r][c][i] * alpha + bv_);
      }
    }
  } else {
    float* Cf = (float*)C + (long)batch * sC;
#pragma unroll
    for (int r = 0; r < 4; r++) {
      const int row = rowBase + r * 16 + quad * 4;
#pragma unroll
      for (int c = 0; c < 4; c++) {
        const int col = colBase + c * 16 + lm;
        const float bv_ = HAS_BIAS ? bias[col] : 0.f;
#pragma unroll
        for (int i = 0; i < 4; i++)
          Cf[(long)(row + i) * ldc + col] = acc[r][c][i] * alpha + bv_;
      }
    }
  }
}

extern "C" void kernel_launch(void* const* d_in, const int* in_sizes, int n_in,
                              void* d_out, int out_size, void* d_ws, size_t ws_size,
                              hipStream_t stream) {
  const float* x  = (const float*)d_in[0];
  const float* Wq = (const float*)d_in[1];
  const float* bq = (const float*)d_in[2];
  const float* Wk = (const float*)d_in[3];
  const float* bk = (const float*)d_in[4];
  const float* Wv = (const float*)d_in[5];
  const float* bv = (const float*)d_in[6];
  const float* Wo = (const float*)d_in[7];
  const float* bo = (const float*)d_in[8];
  float* out = (float*)d_out;

  const long NX = 8192L * 1024;      // 8M elems
  const long NW = 1024L * 1024;      // 1M elems

  bf16_t* ws  = (bf16_t*)d_ws;
  bf16_t* xb  = ws;                  // NX
  bf16_t* Wqb = xb + NX;
  bf16_t* Wkb = Wqb + NW;
  bf16_t* Wvb = Wkb + NW;
  bf16_t* Wob = Wvb + NW;
  bf16_t* qb  = Wob + NW;            // NX
  bf16_t* kT  = qb + NX;             // NX [B][E][S]
  bf16_t* vT  = kT + NX;             // NX [B][E][S]
  // reuse (stream-ordered):
  bf16_t* MtTb = xb;                 // 4M: [B][f][e], xb dead after qkv3
  bf16_t* Gb   = vT;                 // 4M: [B][i][f], vT dead after M gemm

  CvtArgs ca;
  ca.seg[0] = {x,  xb,  NX};
  ca.seg[1] = {Wq, Wqb, NW};
  ca.seg[2] = {Wk, Wkb, NW};
  ca.seg[3] = {Wv, Wvb, NW};
  ca.seg[4] = {Wo, Wob, NW};
  cvt_multi<<<dim3(2048, 5), 256, 0, stream>>>(ca);

  // q / kT / vT fused, 128x128, 2 blocks/CU (round-5 proven: ~60us)
  qkv3<<<dim3(512), 256, 0, stream>>>(xb, Wqb, Wkb, Wvb, bq, bk, bv, qb, kT, vT);

  // MtT[f,e] = 0.125 * sum_t kT[f,t]*vT[e,t]; K=2048, BK=64 -> nk=32; 256 blocks
  gemm64<0, false, 256, 64><<<dim3(256), 256, 0, stream>>>(
      kT, vT, MtTb, nullptr, 2048, 2048, 32,
      1024L * 2048, 1024L * 2048, 1024L * 1024, 1024, 0.125f);

  // G[i,f] = sum_e Wo[i,e] * MtT[f,e]; K=1024 -> nk=16; 256 blocks
  gemm64<0, false, 256, 64><<<dim3(256), 256, 0, stream>>>(
      Wob, MtTb, Gb, nullptr, 1024, 1024, 16,
      0L, 1024L * 1024, 1024L * 1024, 1024, 1.0f);

  // out[s,i] = sum_f q[s,f] * G[i,f] + bo[i]; K=1024 -> nk=16; 512 blocks (2/CU)
  gemm64<2, true, 512, 128><<<dim3(512), 256, 0, stream>>>(
      qb, Gb, out, bo, 1024, 1024, 16,
      2048L * 1024, 1024L * 1024, 2048L * 1024, 1024, 1.0f);
}